// Round 4
// baseline (313.283 us; speedup 1.0000x reference)
//
#include <hip/hip_runtime.h>
#include <hip/hip_bf16.h>
#include <stdint.h>

#define IN_F   4096
#define OUT_F  4096
#define M_ROWS 2048
#define LORA_SCALE 2.0f   // 32.0 / 16

typedef __bf16 bf16x8 __attribute__((ext_vector_type(8)));
typedef float  f32x4  __attribute__((ext_vector_type(4)));

typedef const __attribute__((address_space(1))) void gvoid_t;
typedef __attribute__((address_space(3))) void lvoid_t;

// ---------- 1. fused prep: dequant W -> bf16, cast x -> bf16, t = x@A^T (fp32)
__global__ void prep_kernel(const int* __restrict__ qw,
                            const float* __restrict__ scales,
                            __hip_bfloat16* __restrict__ W,
                            const float* __restrict__ x,
                            __hip_bfloat16* __restrict__ xb,
                            const float* __restrict__ A,
                            float* __restrict__ tout) {
    int b = blockIdx.x;
    if (b < 8192) {
        // dequant: 4 packed bytes (one per int32) -> 8 bf16 weights
        int t = b * 256 + threadIdx.x;
        int4 q = ((const int4*)qw)[t];
        float scale = scales[t >> 3];           // 32 packed bytes per 64-weight block
        float step = scale * (2.0f / 15.0f);
        int bb[4] = {q.x, q.y, q.z, q.w};
        union { __hip_bfloat16 h[8]; uint4 v; } o;
        #pragma unroll
        for (int j = 0; j < 4; ++j) {
            float lo = (float)(bb[j] & 15)        * step - scale;
            float hi = (float)((bb[j] >> 4) & 15) * step - scale;
            o.h[2*j]   = __float2bfloat16(lo);
            o.h[2*j+1] = __float2bfloat16(hi);
        }
        ((uint4*)W)[t] = o.v;
    } else if (b < 12288) {
        // xcast: 8 floats -> 8 bf16 per thread
        int t = (b - 8192) * 256 + threadIdx.x;
        float4 a = ((const float4*)x)[2*t];
        float4 c = ((const float4*)x)[2*t + 1];
        union { __hip_bfloat16 h[8]; uint4 v; } o;
        o.h[0] = __float2bfloat16(a.x); o.h[1] = __float2bfloat16(a.y);
        o.h[2] = __float2bfloat16(a.z); o.h[3] = __float2bfloat16(a.w);
        o.h[4] = __float2bfloat16(c.x); o.h[5] = __float2bfloat16(c.y);
        o.h[6] = __float2bfloat16(c.z); o.h[7] = __float2bfloat16(c.w);
        ((uint4*)xb)[t] = o.v;
    } else {
        // lora t[m][r] = sum_k x[m][k]*A[r][k], 4 rows per block
        __shared__ float red[16 * 4 * 16];
        int m0 = (b - 12288) * 4;
        int r = threadIdx.x & 15;
        int g = threadIdx.x >> 4;
        float acc[4] = {0.f, 0.f, 0.f, 0.f};
        for (int kb = 0; kb < 64; ++kb) {
            int k = kb * 64 + g * 4;
            float4 av = *(const float4*)(A + (size_t)r * IN_F + k);
            #pragma unroll
            for (int row = 0; row < 4; ++row) {
                float4 xv = *(const float4*)(x + (size_t)(m0 + row) * IN_F + k);
                acc[row] += xv.x*av.x + xv.y*av.y + xv.z*av.z + xv.w*av.w;
            }
        }
        #pragma unroll
        for (int row = 0; row < 4; ++row) red[g*64 + row*16 + r] = acc[row];
        __syncthreads();
        if (threadIdx.x < 64) {
            int row = threadIdx.x >> 4, rr = threadIdx.x & 15;
            float s = 0.f;
            #pragma unroll
            for (int gg = 0; gg < 16; ++gg) s += red[gg*64 + row*16 + rr];
            tout[(size_t)(m0 + row) * 16 + rr] = s;
        }
    }
}

// ---------- 2. GEMM: out = Xb @ Wb^T + bias + 2*(t @ loraB^T)
// 256 threads = 4 waves; 128x128 tile; per-wave 4x4 of 16x16x32 MFMA tiles
// (8 fragment reads feed 16 MFMAs -> 0.5 KB LDS per MFMA, LDS-balanced).
// BK=64, XOR-swizzled LDS (conflict-free b128), double-buffered, 1 barrier/iter.
__global__ __launch_bounds__(256) void gemm_kernel(
        const __hip_bfloat16* __restrict__ A,     // [M, K] bf16
        const __hip_bfloat16* __restrict__ B,     // [N, K] bf16 (= W)
        const float* __restrict__ bias,           // [N]
        const float* __restrict__ loraB,          // [N, 16]
        const float* __restrict__ tmat,           // [M, 16]
        float* __restrict__ out) {                // [M, N]
    const int K = IN_F, N = OUT_F;
    __shared__ union alignas(16) {
        struct { __hip_bfloat16 As[2][128*64]; __hip_bfloat16 Bs[2][128*64]; } s; // 64 KB
        float tstage[128 * 16];                                                   //  8 KB
    } sm;

    int tid  = threadIdx.x;
    int wave = tid >> 6, lane = tid & 63;
    int wm = wave >> 1, wn = wave & 1;            // 2x2 wave grid over 128x128
    int row16 = lane & 15, quad = lane >> 4;
    int r7 = row16 & 7;                           // swizzle key (matches writer's row&7)
    int m0 = blockIdx.y * 128, n0 = blockIdx.x * 128;

    // DMA mapping: lane i covers row (seg*8 + i>>3), 16B-chunk ((i&7) ^ (i>>3 & 7))
    int rl = lane >> 3;                // 0..7 row-within-8-row-segment
    int cg = (lane & 7) ^ rl;          // swizzled global chunk (16B units)

    // A/B: 16 segments of 8 rows each; wave stages segs {wave*4 .. wave*4+3}
    const __hip_bfloat16* pA = A + (size_t)(m0 + wave*32 + rl) * K + cg*8;
    const __hip_bfloat16* pB = B + (size_t)(n0 + wave*32 + rl) * K + cg*8;

    f32x4 acc[4][4];
    #pragma unroll
    for (int i = 0; i < 4; ++i)
        #pragma unroll
        for (int j = 0; j < 4; ++j) acc[i][j] = (f32x4){0.f, 0.f, 0.f, 0.f};

    // prologue: stage k0=0 into buffer 0
    #pragma unroll
    for (int j = 0; j < 4; ++j) {
        __builtin_amdgcn_global_load_lds((gvoid_t*)(pA + (size_t)j*8*K),
            (lvoid_t*)&sm.s.As[0][(wave*4 + j) * 512], 16, 0, 0);
        __builtin_amdgcn_global_load_lds((gvoid_t*)(pB + (size_t)j*8*K),
            (lvoid_t*)&sm.s.Bs[0][(wave*4 + j) * 512], 16, 0, 0);
    }
    __syncthreads();

    for (int k0 = 0; k0 < K; k0 += 64) {
        int cur = (k0 >> 6) & 1;
        if (k0 + 64 < K) {   // prefetch next slab into other buffer (flies during compute)
            #pragma unroll
            for (int j = 0; j < 4; ++j) {
                __builtin_amdgcn_global_load_lds((gvoid_t*)(pA + k0 + 64 + (size_t)j*8*K),
                    (lvoid_t*)&sm.s.As[cur^1][(wave*4 + j) * 512], 16, 0, 0);
                __builtin_amdgcn_global_load_lds((gvoid_t*)(pB + k0 + 64 + (size_t)j*8*K),
                    (lvoid_t*)&sm.s.Bs[cur^1][(wave*4 + j) * 512], 16, 0, 0);
            }
        }

        #pragma unroll
        for (int s = 0; s < 2; ++s) {            // two 16x16x32 k-steps per 64-k slab
            bf16x8 af[4], bfr[4];
            #pragma unroll
            for (int mt = 0; mt < 4; ++mt) {
                int row = wm*64 + mt*16 + row16;
                af[mt] = *(const bf16x8*)&sm.s.As[cur][row*64 + ((s*4 + quad) ^ r7) * 8];
            }
            #pragma unroll
            for (int nt = 0; nt < 4; ++nt) {
                int row = wn*64 + nt*16 + row16;
                bfr[nt] = *(const bf16x8*)&sm.s.Bs[cur][row*64 + ((s*4 + quad) ^ r7) * 8];
            }
            #pragma unroll
            for (int mt = 0; mt < 4; ++mt)
                #pragma unroll
                for (int nt = 0; nt < 4; ++nt)
                    acc[mt][nt] = __builtin_amdgcn_mfma_f32_16x16x32_bf16(
                        af[mt], bfr[nt], acc[mt][nt], 0, 0, 0);
        }

        __syncthreads();   // protects buffer reuse + prefetch arrival
    }

    // stage t rows for this m-block: 128 x 16 fp32 = 512 float4
    #pragma unroll
    for (int i = 0; i < 2; ++i)
        ((float4*)sm.tstage)[tid + i*256] =
            ((const float4*)(tmat + (size_t)m0 * 16))[tid + i*256];
    __syncthreads();

    #pragma unroll
    for (int nt = 0; nt < 4; ++nt) {
        int nl = wn*64 + nt*16 + row16;
        int n  = n0 + nl;
        float bn = bias[n];
        const float4* lb = (const float4*)(loraB + (size_t)n * 16);
        float4 lb0 = lb[0], lb1 = lb[1], lb2 = lb[2], lb3 = lb[3];
        #pragma unroll
        for (int mt = 0; mt < 4; ++mt) {
            #pragma unroll
            for (int r = 0; r < 4; ++r) {
                int ml = wm*64 + mt*16 + quad*4 + r;
                const float* tm = &sm.tstage[ml * 16];
                float dot =
                    tm[0]*lb0.x + tm[1]*lb0.y + tm[2]*lb0.z + tm[3]*lb0.w +
                    tm[4]*lb1.x + tm[5]*lb1.y + tm[6]*lb1.z + tm[7]*lb1.w +
                    tm[8]*lb2.x + tm[9]*lb2.y + tm[10]*lb2.z + tm[11]*lb2.w +
                    tm[12]*lb3.x + tm[13]*lb3.y + tm[14]*lb3.z + tm[15]*lb3.w;
                out[(size_t)(m0 + ml) * N + n] = acc[mt][nt][r] + bn + LORA_SCALE * dot;
            }
        }
    }
}

extern "C" void kernel_launch(void* const* d_in, const int* in_sizes, int n_in,
                              void* d_out, int out_size, void* d_ws, size_t ws_size,
                              hipStream_t stream) {
    const float* x      = (const float*)d_in[0];   // [2,1024,4096]
    const int*   qw     = (const int*)d_in[1];     // [8388608] one byte each
    const float* scales = (const float*)d_in[2];   // [262144]
    const float* bias   = (const float*)d_in[3];   // [4096]
    const float* loraA  = (const float*)d_in[4];   // [16,4096]
    const float* loraB  = (const float*)d_in[5];   // [4096,16]
    float* out = (float*)d_out;

    char* ws = (char*)d_ws;
    __hip_bfloat16* Wb = (__hip_bfloat16*)ws;                           // 33,554,432 B
    __hip_bfloat16* Xb = (__hip_bfloat16*)(ws + 33554432);              // 16,777,216 B
    float* tmat        = (float*)(ws + 33554432 + 16777216);            //    131,072 B

    prep_kernel<<<12800, 256, 0, stream>>>(qw, scales, Wb, x, Xb, loraA, tmat);
    gemm_kernel<<<dim3(32, 16), 256, 0, stream>>>(Xb, Wb, bias, loraB, tmat, out);
}

// Round 5
// 296.788 us; speedup vs baseline: 1.0556x; 1.0556x over previous
//
#include <hip/hip_runtime.h>
#include <hip/hip_bf16.h>
#include <stdint.h>

#define IN_F   4096
#define OUT_F  4096
#define M_ROWS 2048
#define LORA_SCALE 2.0f   // 32.0 / 16

typedef __bf16 bf16x8 __attribute__((ext_vector_type(8)));
typedef float  f32x4  __attribute__((ext_vector_type(4)));

typedef const __attribute__((address_space(1))) void gvoid_t;
typedef __attribute__((address_space(3))) void lvoid_t;

// ---------- 1. fused prep: dequant W -> bf16, cast x -> bf16, t = x@A^T (fp32)
__global__ void prep_kernel(const int* __restrict__ qw,
                            const float* __restrict__ scales,
                            __hip_bfloat16* __restrict__ W,
                            const float* __restrict__ x,
                            __hip_bfloat16* __restrict__ xb,
                            const float* __restrict__ A,
                            float* __restrict__ tout) {
    int b = blockIdx.x;
    if (b < 8192) {
        // dequant: 4 packed bytes (one per int32) -> 8 bf16 weights
        int t = b * 256 + threadIdx.x;
        int4 q = ((const int4*)qw)[t];
        float scale = scales[t >> 3];           // 32 packed bytes per 64-weight block
        float step = scale * (2.0f / 15.0f);
        int bb[4] = {q.x, q.y, q.z, q.w};
        union { __hip_bfloat16 h[8]; uint4 v; } o;
        #pragma unroll
        for (int j = 0; j < 4; ++j) {
            float lo = (float)(bb[j] & 15)        * step - scale;
            float hi = (float)((bb[j] >> 4) & 15) * step - scale;
            o.h[2*j]   = __float2bfloat16(lo);
            o.h[2*j+1] = __float2bfloat16(hi);
        }
        ((uint4*)W)[t] = o.v;
    } else if (b < 12288) {
        // xcast: 8 floats -> 8 bf16 per thread
        int t = (b - 8192) * 256 + threadIdx.x;
        float4 a = ((const float4*)x)[2*t];
        float4 c = ((const float4*)x)[2*t + 1];
        union { __hip_bfloat16 h[8]; uint4 v; } o;
        o.h[0] = __float2bfloat16(a.x); o.h[1] = __float2bfloat16(a.y);
        o.h[2] = __float2bfloat16(a.z); o.h[3] = __float2bfloat16(a.w);
        o.h[4] = __float2bfloat16(c.x); o.h[5] = __float2bfloat16(c.y);
        o.h[6] = __float2bfloat16(c.z); o.h[7] = __float2bfloat16(c.w);
        ((uint4*)xb)[t] = o.v;
    } else {
        // lora t[m][r] = sum_k x[m][k]*A[r][k], 4 rows per block
        __shared__ float red[16 * 4 * 16];
        int m0 = (b - 12288) * 4;
        int r = threadIdx.x & 15;
        int g = threadIdx.x >> 4;
        float acc[4] = {0.f, 0.f, 0.f, 0.f};
        for (int kb = 0; kb < 64; ++kb) {
            int k = kb * 64 + g * 4;
            float4 av = *(const float4*)(A + (size_t)r * IN_F + k);
            #pragma unroll
            for (int row = 0; row < 4; ++row) {
                float4 xv = *(const float4*)(x + (size_t)(m0 + row) * IN_F + k);
                acc[row] += xv.x*av.x + xv.y*av.y + xv.z*av.z + xv.w*av.w;
            }
        }
        #pragma unroll
        for (int row = 0; row < 4; ++row) red[g*64 + row*16 + r] = acc[row];
        __syncthreads();
        if (threadIdx.x < 64) {
            int row = threadIdx.x >> 4, rr = threadIdx.x & 15;
            float s = 0.f;
            #pragma unroll
            for (int gg = 0; gg < 16; ++gg) s += red[gg*64 + row*16 + rr];
            tout[(size_t)(m0 + row) * 16 + rr] = s;
        }
    }
}

// ---------- 2. Split-K GEMM: partial[m][n] = sum_{k in half} Xb[m][k]*W[n][k]
// m97 shape: 256 thr / 4 waves, 128x128 tile, 4x4 acc of 16x16x32, BK=32,
// double-buffered 32 KB LDS, exact-2-way XOR swizzle, plain stores (no epilogue).
// gridDim.z picks the K-half; z=0 -> out0, z=1 -> p1.
__global__ __launch_bounds__(256) void gemm_kernel(
        const __hip_bfloat16* __restrict__ A,     // [M, K] bf16
        const __hip_bfloat16* __restrict__ B,     // [N, K] bf16 (= W)
        float* __restrict__ out0,                 // [M, N] partial (z=0)
        float* __restrict__ p1) {                 // [M, N] partial (z=1)
    const int K = IN_F, N = OUT_F;
    const int KHALF = 2048;
    __shared__ __hip_bfloat16 As[2][128*32];      // 16 KB
    __shared__ __hip_bfloat16 Bs[2][128*32];      // 16 KB

    int tid  = threadIdx.x;
    int wave = tid >> 6, lane = tid & 63;
    int wm = wave >> 1, wn = wave & 1;            // 2x2 wave grid over 128x128
    int row16 = lane & 15, quad = lane >> 4;
    int m0 = blockIdx.y * 128, n0 = blockIdx.x * 128;
    int kb = blockIdx.z * KHALF;

    // DMA mapping: lane i covers row (seg*16 + i>>2), 16B-chunk ((i&3) ^ ((row>>1)&3))
    int rl = lane >> 2;                           // 0..15 row within 16-row segment
    int cg = (lane & 3) ^ ((rl >> 1) & 3);        // swizzled chunk (16B units)

    // 8 segments of 16 rows; wave stages segs {wave*2, wave*2+1} for A and B
    const __hip_bfloat16* pA = A + (size_t)(m0 + wave*32 + rl) * K + kb + cg*8;
    const __hip_bfloat16* pB = B + (size_t)(n0 + wave*32 + rl) * K + kb + cg*8;

    f32x4 acc[4][4];
    #pragma unroll
    for (int i = 0; i < 4; ++i)
        #pragma unroll
        for (int j = 0; j < 4; ++j) acc[i][j] = (f32x4){0.f, 0.f, 0.f, 0.f};

    // prologue: stage slab 0 into buffer 0
    #pragma unroll
    for (int j = 0; j < 2; ++j) {
        __builtin_amdgcn_global_load_lds((gvoid_t*)(pA + (size_t)j*16*K),
            (lvoid_t*)&As[0][(wave*2 + j) * 512], 16, 0, 0);
        __builtin_amdgcn_global_load_lds((gvoid_t*)(pB + (size_t)j*16*K),
            (lvoid_t*)&Bs[0][(wave*2 + j) * 512], 16, 0, 0);
    }
    __syncthreads();

    for (int k0 = 0; k0 < KHALF; k0 += 32) {
        int cur = (k0 >> 5) & 1;
        if (k0 + 32 < KHALF) {   // prefetch next slab into other buffer
            #pragma unroll
            for (int j = 0; j < 2; ++j) {
                __builtin_amdgcn_global_load_lds((gvoid_t*)(pA + k0 + 32 + (size_t)j*16*K),
                    (lvoid_t*)&As[cur^1][(wave*2 + j) * 512], 16, 0, 0);
                __builtin_amdgcn_global_load_lds((gvoid_t*)(pB + k0 + 32 + (size_t)j*16*K),
                    (lvoid_t*)&Bs[cur^1][(wave*2 + j) * 512], 16, 0, 0);
            }
        }

        bf16x8 af[4], bfr[4];
        #pragma unroll
        for (int mt = 0; mt < 4; ++mt) {
            int row = wm*64 + mt*16 + row16;
            af[mt] = *(const bf16x8*)&As[cur][row*32 + ((quad ^ ((row >> 1) & 3)) << 3)];
        }
        #pragma unroll
        for (int nt = 0; nt < 4; ++nt) {
            int row = wn*64 + nt*16 + row16;
            bfr[nt] = *(const bf16x8*)&Bs[cur][row*32 + ((quad ^ ((row >> 1) & 3)) << 3)];
        }
        #pragma unroll
        for (int mt = 0; mt < 4; ++mt)
            #pragma unroll
            for (int nt = 0; nt < 4; ++nt)
                acc[mt][nt] = __builtin_amdgcn_mfma_f32_16x16x32_bf16(
                    af[mt], bfr[nt], acc[mt][nt], 0, 0, 0);

        __syncthreads();   // protects buffer reuse + prefetch arrival
    }

    float* dst = blockIdx.z ? p1 : out0;
    #pragma unroll
    for (int nt = 0; nt < 4; ++nt) {
        int n = n0 + wn*64 + nt*16 + row16;
        #pragma unroll
        for (int mt = 0; mt < 4; ++mt) {
            #pragma unroll
            for (int r = 0; r < 4; ++r) {
                int ml = wm*64 + mt*16 + quad*4 + r;
                dst[(size_t)(m0 + ml) * N + n] = acc[mt][nt][r];
            }
        }
    }
}

// ---------- 3. epilogue: out = out + p1 + bias + 2*(t @ loraB^T)
// block tile: 16 m x 64 n; thread owns one n, 4 m's; t via LDS broadcast.
__global__ __launch_bounds__(256) void epilogue_kernel(
        float* __restrict__ out, const float* __restrict__ p1,
        const float* __restrict__ bias, const float* __restrict__ loraB,
        const float* __restrict__ tmat) {
    const int N = OUT_F;
    __shared__ float tl[16 * 16];
    int m0 = blockIdx.y * 16, n0 = blockIdx.x * 64;
    int tid = threadIdx.x;
    if (tid < 64) ((float4*)tl)[tid] = ((const float4*)(tmat + (size_t)m0 * 16))[tid];
    __syncthreads();

    int nl = tid & 63, mq = tid >> 6;
    int n = n0 + nl;
    const float4* lb = (const float4*)(loraB + (size_t)n * 16);
    float4 b0 = lb[0], b1 = lb[1], b2 = lb[2], b3 = lb[3];
    float bn = bias[n];

    #pragma unroll
    for (int j = 0; j < 4; ++j) {
        int ml = mq * 4 + j;
        const float* tm = &tl[ml * 16];           // wave-uniform -> LDS broadcast
        float dot =
            tm[0]*b0.x + tm[1]*b0.y + tm[2]*b0.z + tm[3]*b0.w +
            tm[4]*b1.x + tm[5]*b1.y + tm[6]*b1.z + tm[7]*b1.w +
            tm[8]*b2.x + tm[9]*b2.y + tm[10]*b2.z + tm[11]*b2.w +
            tm[12]*b3.x + tm[13]*b3.y + tm[14]*b3.z + tm[15]*b3.w;
        size_t off = (size_t)(m0 + ml) * N + n;
        out[off] = out[off] + p1[off] + bn + LORA_SCALE * dot;
    }
}

extern "C" void kernel_launch(void* const* d_in, const int* in_sizes, int n_in,
                              void* d_out, int out_size, void* d_ws, size_t ws_size,
                              hipStream_t stream) {
    const float* x      = (const float*)d_in[0];   // [2,1024,4096]
    const int*   qw     = (const int*)d_in[1];     // [8388608] one byte each
    const float* scales = (const float*)d_in[2];   // [262144]
    const float* bias   = (const float*)d_in[3];   // [4096]
    const float* loraA  = (const float*)d_in[4];   // [16,4096]
    const float* loraB  = (const float*)d_in[5];   // [4096,16]
    float* out = (float*)d_out;

    char* ws = (char*)d_ws;
    __hip_bfloat16* Wb = (__hip_bfloat16*)ws;                 // 33,554,432 B
    __hip_bfloat16* Xb = (__hip_bfloat16*)(ws + 33554432);    // 16,777,216 B
    float* tmat        = (float*)(ws + 50331648);             //    131,072 B
    float* p1          = (float*)(ws + 50462720);             // 33,554,432 B (split-K partial)

    prep_kernel    <<<12800, 256, 0, stream>>>(qw, scales, Wb, x, Xb, loraA, tmat);
    gemm_kernel    <<<dim3(32, 16, 2), 256, 0, stream>>>(Xb, Wb, out, p1);
    epilogue_kernel<<<dim3(64, 128), 256, 0, stream>>>(out, p1, bias, loraB, tmat);
}

// Round 8
// 264.267 us; speedup vs baseline: 1.1855x; 1.1231x over previous
//
#include <hip/hip_runtime.h>
#include <hip/hip_bf16.h>
#include <stdint.h>

#define IN_F   4096
#define OUT_F  4096
#define M_ROWS 2048
#define LORA_SCALE 2.0f   // 32.0 / 16

typedef __bf16 bf16x8 __attribute__((ext_vector_type(8)));
typedef float  f32x4  __attribute__((ext_vector_type(4)));

typedef const __attribute__((address_space(1))) void gvoid_t;
typedef __attribute__((address_space(3))) void lvoid_t;

// ---------- 1. fused prep: lora t = x@A^T (blocks 0-511, launched first so the
// serial-loop blocks don't become a tail), dequant W (512-8703), xcast (8704-12799)
__global__ void prep_kernel(const int* __restrict__ qw,
                            const float* __restrict__ scales,
                            __hip_bfloat16* __restrict__ W,
                            const float* __restrict__ x,
                            __hip_bfloat16* __restrict__ xb,
                            const float* __restrict__ A,
                            float* __restrict__ tout) {
    int b = blockIdx.x;
    if (b < 512) {
        // lora t[m][r] = sum_k x[m][k]*A[r][k], 4 rows per block
        __shared__ float red[16 * 4 * 16];
        int m0 = b * 4;
        int r = threadIdx.x & 15;
        int g = threadIdx.x >> 4;
        float acc[4] = {0.f, 0.f, 0.f, 0.f};
        for (int kb = 0; kb < 64; ++kb) {
            int k = kb * 64 + g * 4;
            float4 av = *(const float4*)(A + (size_t)r * IN_F + k);
            #pragma unroll
            for (int row = 0; row < 4; ++row) {
                float4 xv = *(const float4*)(x + (size_t)(m0 + row) * IN_F + k);
                acc[row] += xv.x*av.x + xv.y*av.y + xv.z*av.z + xv.w*av.w;
            }
        }
        #pragma unroll
        for (int row = 0; row < 4; ++row) red[g*64 + row*16 + r] = acc[row];
        __syncthreads();
        if (threadIdx.x < 64) {
            int row = threadIdx.x >> 4, rr = threadIdx.x & 15;
            float s = 0.f;
            #pragma unroll
            for (int gg = 0; gg < 16; ++gg) s += red[gg*64 + row*16 + rr];
            tout[(size_t)(m0 + row) * 16 + rr] = s;
        }
    } else if (b < 8704) {
        // dequant: 4 packed bytes (one per int32) -> 8 bf16 weights
        int t = (b - 512) * 256 + threadIdx.x;
        int4 q = ((const int4*)qw)[t];
        float scale = scales[t >> 3];           // 32 packed bytes per 64-weight block
        float step = scale * (2.0f / 15.0f);
        int bb[4] = {q.x, q.y, q.z, q.w};
        union { __hip_bfloat16 h[8]; uint4 v; } o;
        #pragma unroll
        for (int j = 0; j < 4; ++j) {
            float lo = (float)(bb[j] & 15)        * step - scale;
            float hi = (float)((bb[j] >> 4) & 15) * step - scale;
            o.h[2*j]   = __float2bfloat16(lo);
            o.h[2*j+1] = __float2bfloat16(hi);
        }
        ((uint4*)W)[t] = o.v;
    } else {
        // xcast: 8 floats -> 8 bf16 per thread
        int t = (b - 8704) * 256 + threadIdx.x;
        float4 a = ((const float4*)x)[2*t];
        float4 c = ((const float4*)x)[2*t + 1];
        union { __hip_bfloat16 h[8]; uint4 v; } o;
        o.h[0] = __float2bfloat16(a.x); o.h[1] = __float2bfloat16(a.y);
        o.h[2] = __float2bfloat16(a.z); o.h[3] = __float2bfloat16(a.w);
        o.h[4] = __float2bfloat16(c.x); o.h[5] = __float2bfloat16(c.y);
        o.h[6] = __float2bfloat16(c.z); o.h[7] = __float2bfloat16(c.w);
        ((uint4*)xb)[t] = o.v;
    }
}

// ---------- 2. Split-K GEMM, x2-unrolled parity loop
// 256 thr / 4 waves, 128x128 tile, 4x4 acc of 16x16x32, BK=32,
// dbuf 32 KB LDS, exact-2-way XOR swizzle (0 conflicts, verified R5).
// ALL global_load_lds use offset=0 (non-zero imm offset produced wrong data in
// R7 — ISA applies the LDS-DMA inst offset on the LDS side, not global);
// addresses advance via explicit pointer bumps instead.
__global__ __launch_bounds__(256) void gemm_kernel(
        const __hip_bfloat16* __restrict__ A,     // [M, K] bf16
        const __hip_bfloat16* __restrict__ B,     // [N, K] bf16 (= W)
        float* __restrict__ out0,                 // [M, N] partial (z=0)
        float* __restrict__ p1) {                 // [M, N] partial (z=1)
    const int K = IN_F, N = OUT_F;
    __shared__ __hip_bfloat16 As[2][128*32];      // 16 KB
    __shared__ __hip_bfloat16 Bs[2][128*32];      // 16 KB

    int tid  = threadIdx.x;
    int wave = tid >> 6, lane = tid & 63;
    int wm = wave >> 1, wn = wave & 1;            // 2x2 wave grid over 128x128
    int row16 = lane & 15, quad = lane >> 4;
    int m0 = blockIdx.y * 128, n0 = blockIdx.x * 128;
    int kb = blockIdx.z * 2048;

    // DMA mapping: lane i covers row (seg*16 + i>>2), 16B-chunk ((i&3) ^ ((row>>1)&3))
    int rl = lane >> 2;                           // 0..15 row within 16-row segment
    int cg = (lane & 3) ^ ((rl >> 1) & 3);        // swizzled chunk (16B units)

    // 4 persistent DMA pointers (A segs wave*2, wave*2+1; same for B)
    const __hip_bfloat16* pA0 = A + (size_t)(m0 + wave*32 + rl) * K + kb + cg*8;
    const __hip_bfloat16* pA1 = pA0 + (size_t)16 * K;
    const __hip_bfloat16* pB0 = B + (size_t)(n0 + wave*32 + rl) * K + kb + cg*8;
    const __hip_bfloat16* pB1 = pB0 + (size_t)16 * K;

    // wave-uniform LDS destinations
    lvoid_t* dA0[2] = { (lvoid_t*)&As[0][(wave*2+0)*512], (lvoid_t*)&As[1][(wave*2+0)*512] };
    lvoid_t* dA1[2] = { (lvoid_t*)&As[0][(wave*2+1)*512], (lvoid_t*)&As[1][(wave*2+1)*512] };
    lvoid_t* dB0[2] = { (lvoid_t*)&Bs[0][(wave*2+0)*512], (lvoid_t*)&Bs[1][(wave*2+0)*512] };
    lvoid_t* dB1[2] = { (lvoid_t*)&Bs[0][(wave*2+1)*512], (lvoid_t*)&Bs[1][(wave*2+1)*512] };

    f32x4 acc[4][4];
    #pragma unroll
    for (int i = 0; i < 4; ++i)
        #pragma unroll
        for (int j = 0; j < 4; ++j) acc[i][j] = (f32x4){0.f, 0.f, 0.f, 0.f};

    // one 16x16x32 k-step over the 32-wide slab in buffer `buf`
    #define COMPUTE(buf)                                                          \
    {                                                                             \
        bf16x8 af[4], bfr[4];                                                     \
        _Pragma("unroll")                                                         \
        for (int mt = 0; mt < 4; ++mt) {                                          \
            int row = wm*64 + mt*16 + row16;                                      \
            af[mt] = *(const bf16x8*)&As[buf][row*32 + ((quad ^ ((row>>1)&3)) << 3)]; \
        }                                                                         \
        _Pragma("unroll")                                                         \
        for (int nt = 0; nt < 4; ++nt) {                                          \
            int row = wn*64 + nt*16 + row16;                                      \
            bfr[nt] = *(const bf16x8*)&Bs[buf][row*32 + ((quad ^ ((row>>1)&3)) << 3)]; \
        }                                                                         \
        _Pragma("unroll")                                                         \
        for (int mt = 0; mt < 4; ++mt)                                            \
            _Pragma("unroll")                                                     \
            for (int nt = 0; nt < 4; ++nt)                                        \
                acc[mt][nt] = __builtin_amdgcn_mfma_f32_16x16x32_bf16(            \
                    af[mt], bfr[nt], acc[mt][nt], 0, 0, 0);                       \
    }

    // stage next 32-wide slab into buffer `buf`, then advance one slab (64 B)
    #define DMA(buf)                                                              \
        __builtin_amdgcn_global_load_lds((gvoid_t*)pA0, dA0[buf], 16, 0, 0);      \
        __builtin_amdgcn_global_load_lds((gvoid_t*)pA1, dA1[buf], 16, 0, 0);      \
        __builtin_amdgcn_global_load_lds((gvoid_t*)pB0, dB0[buf], 16, 0, 0);      \
        __builtin_amdgcn_global_load_lds((gvoid_t*)pB1, dB1[buf], 16, 0, 0);      \
        pA0 += 32; pA1 += 32; pB0 += 32; pB1 += 32;

    // prologue: slab 0 -> buf0
    DMA(0)
    __syncthreads();

    // main loop: 31 iters; iter i consumes slabs {2i, 2i+1}, prefetches {2i+1, 2i+2}
    for (int i = 0; i < 31; ++i) {
        DMA(1)                     // slab 2i+1 -> buf1, flies during compute
        COMPUTE(0)                 // slab 2i
        __syncthreads();           // drains slab 2i+1
        DMA(0)                     // slab 2i+2 -> buf0
        COMPUTE(1)                 // slab 2i+1
        __syncthreads();           // drains slab 2i+2
    }
    // tail: slabs 62 (buf0, ready) and 63
    DMA(1)
    COMPUTE(0)
    __syncthreads();
    COMPUTE(1)

    #undef COMPUTE
    #undef DMA

    float* dst = blockIdx.z ? p1 : out0;
    #pragma unroll
    for (int nt = 0; nt < 4; ++nt) {
        int n = n0 + wn*64 + nt*16 + row16;
        #pragma unroll
        for (int mt = 0; mt < 4; ++mt) {
            #pragma unroll
            for (int r = 0; r < 4; ++r) {
                int ml = wm*64 + mt*16 + quad*4 + r;
                dst[(size_t)(m0 + ml) * N + n] = acc[mt][nt][r];
            }
        }
    }
}

// ---------- 3. epilogue: out = out + p1 + bias + 2*(t @ loraB^T)
__global__ __launch_bounds__(256) void epilogue_kernel(
        float* __restrict__ out, const float* __restrict__ p1,
        const float* __restrict__ bias, const float* __restrict__ loraB,
        const float* __restrict__ tmat) {
    const int N = OUT_F;
    __shared__ float tl[16 * 16];
    int m0 = blockIdx.y * 16, n0 = blockIdx.x * 64;
    int tid = threadIdx.x;
    if (tid < 64) ((float4*)tl)[tid] = ((const float4*)(tmat + (size_t)m0 * 16))[tid];
    __syncthreads();

    int nl = tid & 63, mq = tid >> 6;
    int n = n0 + nl;
    const float4* lb = (const float4*)(loraB + (size_t)n * 16);
    float4 b0 = lb[0], b1 = lb[1], b2 = lb[2], b3 = lb[3];
    float bn = bias[n];

    #pragma unroll
    for (int j = 0; j < 4; ++j) {
        int ml = mq * 4 + j;
        const float* tm = &tl[ml * 16];           // wave-uniform -> LDS broadcast
        float dot =
            tm[0]*b0.x + tm[1]*b0.y + tm[2]*b0.z + tm[3]*b0.w +
            tm[4]*b1.x + tm[5]*b1.y + tm[6]*b1.z + tm[7]*b1.w +
            tm[8]*b2.x + tm[9]*b2.y + tm[10]*b2.z + tm[11]*b2.w +
            tm[12]*b3.x + tm[13]*b3.y + tm[14]*b3.z + tm[15]*b3.w;
        size_t off = (size_t)(m0 + ml) * N + n;
        out[off] = out[off] + p1[off] + bn + LORA_SCALE * dot;
    }
}

extern "C" void kernel_launch(void* const* d_in, const int* in_sizes, int n_in,
                              void* d_out, int out_size, void* d_ws, size_t ws_size,
                              hipStream_t stream) {
    const float* x      = (const float*)d_in[0];   // [2,1024,4096]
    const int*   qw     = (const int*)d_in[1];     // [8388608] one byte each
    const float* scales = (const float*)d_in[2];   // [262144]
    const float* bias   = (const float*)d_in[3];   // [4096]
    const float* loraA  = (const float*)d_in[4];   // [16,4096]
    const float* loraB  = (const float*)d_in[5];   // [4096,16]
    float* out = (float*)d_out;

    char* ws = (char*)d_ws;
    __hip_bfloat16* Wb = (__hip_bfloat16*)ws;                 // 33,554,432 B
    __hip_bfloat16* Xb = (__hip_bfloat16*)(ws + 33554432);    // 16,777,216 B
    float* tmat        = (float*)(ws + 50331648);             //    131,072 B
    float* p1          = (float*)(ws + 50462720);             // 33,554,432 B (split-K partial)

    prep_kernel    <<<12800, 256, 0, stream>>>(qw, scales, Wb, x, Xb, loraA, tmat);
    gemm_kernel    <<<dim3(32, 16, 2), 256, 0, stream>>>(Xb, Wb, out, p1);
    epilogue_kernel<<<dim3(64, 128), 256, 0, stream>>>(out, p1, bias, loraB, tmat);
}

// Round 10
// 261.793 us; speedup vs baseline: 1.1967x; 1.0094x over previous
//
#include <hip/hip_runtime.h>
#include <hip/hip_bf16.h>
#include <stdint.h>

#define IN_F   4096
#define OUT_F  4096
#define M_ROWS 2048
#define LORA_SCALE 2.0f   // 32.0 / 16

typedef __bf16 bf16x8 __attribute__((ext_vector_type(8)));
typedef float  f32x4  __attribute__((ext_vector_type(4)));

typedef const __attribute__((address_space(1))) void gvoid_t;
typedef __attribute__((address_space(3))) void lvoid_t;

// s_waitcnt imm: vmcnt[3:0]|[15:14], expcnt[6:4]=7 (nowait), lgkmcnt[11:8]=15 (nowait)
#define WAITVM(n) __builtin_amdgcn_s_waitcnt(((n)&0xF) | (((n)>>4)<<14) | (7<<4) | (15<<8))

// ---------- 1. fused prep: lora t = x@A^T (blocks 0-511 first), dequant W, xcast
__global__ void prep_kernel(const int* __restrict__ qw,
                            const float* __restrict__ scales,
                            __hip_bfloat16* __restrict__ W,
                            const float* __restrict__ x,
                            __hip_bfloat16* __restrict__ xb,
                            const float* __restrict__ A,
                            float* __restrict__ tout) {
    int b = blockIdx.x;
    if (b < 512) {
        __shared__ float red[16 * 4 * 16];
        int m0 = b * 4;
        int r = threadIdx.x & 15;
        int g = threadIdx.x >> 4;
        float acc[4] = {0.f, 0.f, 0.f, 0.f};
        for (int kb = 0; kb < 64; ++kb) {
            int k = kb * 64 + g * 4;
            float4 av = *(const float4*)(A + (size_t)r * IN_F + k);
            #pragma unroll
            for (int row = 0; row < 4; ++row) {
                float4 xv = *(const float4*)(x + (size_t)(m0 + row) * IN_F + k);
                acc[row] += xv.x*av.x + xv.y*av.y + xv.z*av.z + xv.w*av.w;
            }
        }
        #pragma unroll
        for (int row = 0; row < 4; ++row) red[g*64 + row*16 + r] = acc[row];
        __syncthreads();
        if (threadIdx.x < 64) {
            int row = threadIdx.x >> 4, rr = threadIdx.x & 15;
            float s = 0.f;
            #pragma unroll
            for (int gg = 0; gg < 16; ++gg) s += red[gg*64 + row*16 + rr];
            tout[(size_t)(m0 + row) * 16 + rr] = s;
        }
    } else if (b < 8704) {
        int t = (b - 512) * 256 + threadIdx.x;
        int4 q = ((const int4*)qw)[t];
        float scale = scales[t >> 3];
        float step = scale * (2.0f / 15.0f);
        int bb[4] = {q.x, q.y, q.z, q.w};
        union { __hip_bfloat16 h[8]; uint4 v; } o;
        #pragma unroll
        for (int j = 0; j < 4; ++j) {
            float lo = (float)(bb[j] & 15)        * step - scale;
            float hi = (float)((bb[j] >> 4) & 15) * step - scale;
            o.h[2*j]   = __float2bfloat16(lo);
            o.h[2*j+1] = __float2bfloat16(hi);
        }
        ((uint4*)W)[t] = o.v;
    } else {
        int t = (b - 8704) * 256 + threadIdx.x;
        float4 a = ((const float4*)x)[2*t];
        float4 c = ((const float4*)x)[2*t + 1];
        union { __hip_bfloat16 h[8]; uint4 v; } o;
        o.h[0] = __float2bfloat16(a.x); o.h[1] = __float2bfloat16(a.y);
        o.h[2] = __float2bfloat16(a.z); o.h[3] = __float2bfloat16(a.w);
        o.h[4] = __float2bfloat16(c.x); o.h[5] = __float2bfloat16(c.y);
        o.h[6] = __float2bfloat16(c.z); o.h[7] = __float2bfloat16(c.w);
        ((uint4*)xb)[t] = o.v;
    }
}

// ---------- 2. Deep-pipelined GEMM: 4 waves, 128x128 tile, BK=32, 4 LDS stages,
// prefetch distance 3, raw s_barrier (no vmcnt(0) drain) + per-wave partial
// vmcnt waits. DMA target buffer always holds slab i-1 (readers provably done
// before the barrier we just passed) -> no overwrite race (the R9 bug).
// Fused epilogue: out = acc + bias + 2*(t @ loraB^T).
__global__ __launch_bounds__(256) void gemm_kernel(
        const __hip_bfloat16* __restrict__ A,     // [M, K] bf16
        const __hip_bfloat16* __restrict__ B,     // [N, K] bf16 (= W)
        const float* __restrict__ bias,           // [N]
        const float* __restrict__ loraB,          // [N, 16]
        const float* __restrict__ tmat,           // [M, 16]
        float* __restrict__ out) {                // [M, N]
    const int K = IN_F, N = OUT_F;
    __shared__ union alignas(16) {
        struct { __hip_bfloat16 As[4][128*32]; __hip_bfloat16 Bs[4][128*32]; } s; // 64 KB
        float tl[128 * 16];                       // 8 KB, overlaps As[0] only
    } sm;

    int tid  = threadIdx.x;
    int wave = tid >> 6, lane = tid & 63;
    int wm = wave >> 1, wn = wave & 1;            // 2x2 wave grid over 128x128
    int row16 = lane & 15, quad = lane >> 4;
    int m0 = blockIdx.y * 128, n0 = blockIdx.x * 128;

    // DMA mapping (verified R5/R8): lane i -> row rl=i>>2 of 16-row segment,
    // global 16B-chunk cg=(i&3)^((rl>>1)&3); LDS lands at base + lane*16.
    int rl = lane >> 2;
    int cg = (lane & 3) ^ ((rl >> 1) & 3);

    // 4 persistent DMA pointers (A segs wave*2, wave*2+1; same for B)
    const __hip_bfloat16* pA0 = A + (size_t)(m0 + wave*32 + rl) * K + cg*8;
    const __hip_bfloat16* pA1 = pA0 + (size_t)16 * K;
    const __hip_bfloat16* pB0 = B + (size_t)(n0 + wave*32 + rl) * K + cg*8;
    const __hip_bfloat16* pB1 = pB0 + (size_t)16 * K;

    f32x4 acc[4][4];
    #pragma unroll
    for (int i = 0; i < 4; ++i)
        #pragma unroll
        for (int j = 0; j < 4; ++j) acc[i][j] = (f32x4){0.f, 0.f, 0.f, 0.f};

    // stage next slab into stage `buf` (4 loads/wave), advance one slab (64 B)
    #define DMA(buf)                                                              \
        __builtin_amdgcn_global_load_lds((gvoid_t*)pA0, (lvoid_t*)&sm.s.As[buf][(wave*2+0)*512], 16, 0, 0); \
        __builtin_amdgcn_global_load_lds((gvoid_t*)pA1, (lvoid_t*)&sm.s.As[buf][(wave*2+1)*512], 16, 0, 0); \
        __builtin_amdgcn_global_load_lds((gvoid_t*)pB0, (lvoid_t*)&sm.s.Bs[buf][(wave*2+0)*512], 16, 0, 0); \
        __builtin_amdgcn_global_load_lds((gvoid_t*)pB1, (lvoid_t*)&sm.s.Bs[buf][(wave*2+1)*512], 16, 0, 0); \
        pA0 += 32; pA1 += 32; pB0 += 32; pB1 += 32;

    // one 16x16x32 k-step over the slab in stage `buf` (verified R8 math)
    #define COMPUTE(buf)                                                          \
    {                                                                             \
        bf16x8 af[4], bfr[4];                                                     \
        _Pragma("unroll")                                                         \
        for (int mt = 0; mt < 4; ++mt) {                                          \
            int row = wm*64 + mt*16 + row16;                                      \
            af[mt] = *(const bf16x8*)&sm.s.As[buf][row*32 + ((quad ^ ((row>>1)&3)) << 3)]; \
        }                                                                         \
        _Pragma("unroll")                                                         \
        for (int nt = 0; nt < 4; ++nt) {                                          \
            int row = wn*64 + nt*16 + row16;                                      \
            bfr[nt] = *(const bf16x8*)&sm.s.Bs[buf][row*32 + ((quad ^ ((row>>1)&3)) << 3)]; \
        }                                                                         \
        _Pragma("unroll")                                                         \
        for (int mt = 0; mt < 4; ++mt)                                            \
            _Pragma("unroll")                                                     \
            for (int nt = 0; nt < 4; ++nt)                                        \
                acc[mt][nt] = __builtin_amdgcn_mfma_f32_16x16x32_bf16(            \
                    af[mt], bfr[nt], acc[mt][nt], 0, 0, 0);                       \
    }

    // one pipeline step: consume slab in stage p, prefetch into stage (p+3)&3
    // (which holds slab i-1: all waves' reads of it completed before the
    // s_barrier we just passed -> safe to overwrite)
    #define STEP(p)                                                               \
        WAITVM(8);                         /* own slab-i loads retired */         \
        __builtin_amdgcn_s_barrier();      /* all waves ditto => slab i in LDS */ \
        __builtin_amdgcn_sched_barrier(0);                                        \
        COMPUTE(p)                                                                \
        DMA((p+3)&3)

    // prologue: slabs 0,1,2 -> stages 0,1,2 (12 loads/wave outstanding)
    DMA(0)
    DMA(1)
    DMA(2)

    // main: groups u=0..30 consume slabs 4u..4u+3, prefetch 4u+3..4u+6
    for (int u = 0; u < 31; ++u) {
        STEP(0)
        STEP(1)
        STEP(2)
        STEP(3)
    }
    // tail: slabs 124..127 (slab 127 issued at p=0; then drain)
    STEP(0)
    WAITVM(8); __builtin_amdgcn_s_barrier(); __builtin_amdgcn_sched_barrier(0);
    COMPUTE(1)
    WAITVM(4); __builtin_amdgcn_s_barrier(); __builtin_amdgcn_sched_barrier(0);
    COMPUTE(2)
    WAITVM(0); __builtin_amdgcn_s_barrier(); __builtin_amdgcn_sched_barrier(0);
    COMPUTE(3)

    #undef STEP
    #undef COMPUTE
    #undef DMA

    // fused epilogue. tl overlaps As[0] (all stage reads are complete: each
    // wave's last ds_reads finished before its final barrier/MFMA waits; only
    // Bs[3]/As[3] are possibly still being read, and tl is disjoint from them).
    #pragma unroll
    for (int i = 0; i < 2; ++i)
        ((float4*)sm.tl)[tid + i*256] =
            ((const float4*)(tmat + (size_t)m0 * 16))[tid + i*256];
    __syncthreads();

    #pragma unroll
    for (int nt = 0; nt < 4; ++nt) {
        int n = n0 + wn*64 + nt*16 + row16;
        float bn = bias[n];
        const float4* lb = (const float4*)(loraB + (size_t)n * 16);
        float4 b0 = lb[0], b1 = lb[1], b2 = lb[2], b3 = lb[3];
        #pragma unroll
        for (int mt = 0; mt < 4; ++mt) {
            #pragma unroll
            for (int r = 0; r < 4; ++r) {
                int ml = wm*64 + mt*16 + quad*4 + r;
                const float* tm = &sm.tl[ml * 16];
                float dot =
                    tm[0]*b0.x + tm[1]*b0.y + tm[2]*b0.z + tm[3]*b0.w +
                    tm[4]*b1.x + tm[5]*b1.y + tm[6]*b1.z + tm[7]*b1.w +
                    tm[8]*b2.x + tm[9]*b2.y + tm[10]*b2.z + tm[11]*b2.w +
                    tm[12]*b3.x + tm[13]*b3.y + tm[14]*b3.z + tm[15]*b3.w;
                out[(size_t)(m0 + ml) * N + n] = acc[mt][nt][r] + bn + LORA_SCALE * dot;
            }
        }
    }
}

extern "C" void kernel_launch(void* const* d_in, const int* in_sizes, int n_in,
                              void* d_out, int out_size, void* d_ws, size_t ws_size,
                              hipStream_t stream) {
    const float* x      = (const float*)d_in[0];   // [2,1024,4096]
    const int*   qw     = (const int*)d_in[1];     // [8388608] one byte each
    const float* scales = (const float*)d_in[2];   // [262144]
    const float* bias   = (const float*)d_in[3];   // [4096]
    const float* loraA  = (const float*)d_in[4];   // [16,4096]
    const float* loraB  = (const float*)d_in[5];   // [4096,16]
    float* out = (float*)d_out;

    char* ws = (char*)d_ws;
    __hip_bfloat16* Wb = (__hip_bfloat16*)ws;                 // 33,554,432 B
    __hip_bfloat16* Xb = (__hip_bfloat16*)(ws + 33554432);    // 16,777,216 B
    float* tmat        = (float*)(ws + 50331648);             //    131,072 B

    prep_kernel<<<12800, 256, 0, stream>>>(qw, scales, Wb, x, Xb, loraA, tmat);
    gemm_kernel<<<dim3(32, 16), 256, 0, stream>>>(Xb, Wb, bias, loraB, tmat, out);
}